// Round 1
// baseline (89.912 us; speedup 1.0000x reference)
//
#include <hip/hip_runtime.h>

// ClusterNet: Q = rownorm(1/(1+dist(z, centroids))), P = rownorm(Q^2 / colsum(Q))
// z: 8192x256 fp32, centroids: 64x256 fp32. out = [Q (8192x64) | P (8192x64)] fp32.

#define M  8192
#define NC 64
#define H  256
#define BM 64
#define BK 64
#define LDT 68   // LDS leading dim: 68 floats keeps float4 reads 16B-aligned

// ---------------- K1: partial squared-distance (split-K by 2) ----------------
// grid = 256 blocks: bx = rowTile*2 + khalf. Each block computes, for 64 rows x
// 64 clusters, sum over 128 of the 256 features of (z-c)^2, written as a raw
// partial into d_out half `khalf` (Q region / P region reused as scratch).
__global__ __launch_bounds__(256) void k1_dist_partial(
    const float* __restrict__ Z, const float* __restrict__ C,
    float* __restrict__ out)
{
    __shared__ float Zt[BK][LDT];   // k-major (transposed) Z tile
    __shared__ float Ct[BK][LDT];   // k-major (transposed) centroid tile
    const int t  = threadIdx.x;
    const int bx = blockIdx.x;
    const int m0 = (bx >> 1) * BM;
    const int khalf = bx & 1;
    const int tx = t & 15, ty = t >> 4;
    const int kl = (t & 15) * 4;    // k offset this thread loads
    const int ml = t >> 4;          // row/col offset (0..15), 4 sweeps of 16

    float acc[4][4] = {};

    for (int chunk = 0; chunk < 2; ++chunk) {
        const int kb = khalf * 128 + chunk * BK;
        #pragma unroll
        for (int s = 0; s < 4; ++s) {
            const int m = ml + 16 * s;                       // 0..63
            float4 v = *(const float4*)&Z[(m0 + m) * H + kb + kl];
            Zt[kl + 0][m] = v.x; Zt[kl + 1][m] = v.y;
            Zt[kl + 2][m] = v.z; Zt[kl + 3][m] = v.w;
            float4 w = *(const float4*)&C[m * H + kb + kl];  // m == cluster idx
            Ct[kl + 0][m] = w.x; Ct[kl + 1][m] = w.y;
            Ct[kl + 2][m] = w.z; Ct[kl + 3][m] = w.w;
        }
        __syncthreads();
        #pragma unroll 8
        for (int kk = 0; kk < BK; ++kk) {
            float4 a4 = *(const float4*)&Zt[kk][ty * 4];   // 4 rows (broadcast across tx)
            float4 b4 = *(const float4*)&Ct[kk][tx * 4];   // 4 cols (2-way = free)
            float ar[4] = {a4.x, a4.y, a4.z, a4.w};
            float br[4] = {b4.x, b4.y, b4.z, b4.w};
            #pragma unroll
            for (int r = 0; r < 4; ++r)
                #pragma unroll
                for (int c = 0; c < 4; ++c) {
                    float d = ar[r] - br[c];
                    acc[r][c] += d * d;
                }
        }
        __syncthreads();
    }

    float* dst = out + (size_t)khalf * (M * NC);
    #pragma unroll
    for (int r = 0; r < 4; ++r) {
        float4 v = make_float4(acc[r][0], acc[r][1], acc[r][2], acc[r][3]);
        *(float4*)&dst[(m0 + ty * 4 + r) * NC + tx * 4] = v;
    }
}

// ---------------- zero the colsum accumulator ----------------
__global__ void k0_zero(float* __restrict__ colsum) {
    colsum[threadIdx.x] = 0.0f;
}

// ---------------- K2: combine partials -> Q, accumulate colsum ----------------
// One wave per row (64 lanes == 64 clusters). 32 rows/block, grid=256.
__global__ __launch_bounds__(256) void k2_q(
    float* __restrict__ out, float* __restrict__ colsum)
{
    __shared__ float cs[NC];
    const int t = threadIdx.x;
    if (t < NC) cs[t] = 0.0f;
    __syncthreads();
    const int lane = t & 63;
    const int wid  = t >> 6;   // 0..3
    const int rowBase = blockIdx.x * 32;
    float local = 0.0f;
    for (int it = 0; it < 8; ++it) {
        const int row = rowBase + it * 4 + wid;
        float p0 = out[row * NC + lane];
        float p1 = out[(size_t)M * NC + row * NC + lane];
        float d  = sqrtf(p0 + p1);
        float q  = 1.0f / (1.0f + d);
        float s = q;
        #pragma unroll
        for (int m = 1; m < 64; m <<= 1) s += __shfl_xor(s, m);
        float Q = q / s;
        out[row * NC + lane] = Q;   // overwrite partial0 in place (read-before-write)
        local += Q;
    }
    atomicAdd(&cs[lane], local);
    __syncthreads();
    if (t < NC) atomicAdd(&colsum[t], cs[t]);
}

// ---------------- K3: P = rownorm(Q^2 / colsum) ----------------
__global__ __launch_bounds__(256) void k3_p(
    float* __restrict__ out, const float* __restrict__ colsum)
{
    const int t = threadIdx.x;
    const int lane = t & 63;
    const int wid  = t >> 6;
    const float invcs = 1.0f / colsum[lane];
    const int rowBase = blockIdx.x * 32;
    for (int it = 0; it < 8; ++it) {
        const int row = rowBase + it * 4 + wid;
        float q  = out[row * NC + lane];
        float pr = q * q * invcs;
        float s = pr;
        #pragma unroll
        for (int m = 1; m < 64; m <<= 1) s += __shfl_xor(s, m);
        out[(size_t)M * NC + row * NC + lane] = pr / s;  // overwrite partial1
    }
}

extern "C" void kernel_launch(void* const* d_in, const int* in_sizes, int n_in,
                              void* d_out, int out_size, void* d_ws, size_t ws_size,
                              hipStream_t stream) {
    const float* Z = (const float*)d_in[0];   // 8192 x 256
    const float* C = (const float*)d_in[1];   // 64 x 256
    float* out = (float*)d_out;               // [Q | P], 2 * 8192 * 64 floats
    float* colsum = (float*)d_ws;             // 64 floats of scratch

    k0_zero<<<1, NC, 0, stream>>>(colsum);
    k1_dist_partial<<<256, 256, 0, stream>>>(Z, C, out);
    k2_q<<<256, 256, 0, stream>>>(out, colsum);
    k3_p<<<256, 256, 0, stream>>>(out, colsum);
}

// Round 2
// 81.454 us; speedup vs baseline: 1.1038x; 1.1038x over previous
//
#include <hip/hip_runtime.h>

// ClusterNet fused: Q = rownorm(1/(1+dist(z,C))), P = rownorm(Q^2/colsum(Q))
// z: 8192x256 fp32, C: 64x256 fp32. out = [Q (8192x64) | P (8192x64)] fp32.
// dist^2 = ||z||^2 + ||c||^2 - 2 z.c  (no cancellation risk: dist^2 ~ 512)

#define M  8192
#define NC 64
#define H  256
#define BM 32

// ---------------- K1: distance + Q + per-block colsum partials ----------------
// grid 256 x 256 threads. lane = cluster; wave w handles k-quarter [64w, 64w+64).
// Centroid quarter lives in 64 VGPRs per lane; z is wave-uniform (scalar loads).
__global__ __launch_bounds__(256, 1) void k1_fused(
    const float* __restrict__ Z, const float* __restrict__ C,
    float* __restrict__ out, float* __restrict__ ws)
{
    __shared__ float pd[4][BM][NC];   // per-wave dot partials (32 KB)
    __shared__ float ncp[4][NC];      // per-wave ||c||^2 partials
    __shared__ float nzs[BM];         // row norms
    __shared__ float csum[4][NC];     // per-wave colsum partials

    const int t    = threadIdx.x;
    const int lane = t & 63;
    const int wid  = __builtin_amdgcn_readfirstlane(t >> 6);  // wave-uniform SGPR
    const int row0 = blockIdx.x * BM;

    // ---- row norms ||z_r||^2: 8 threads per row, shfl-reduce width 8 ----
    {
        const int r  = t >> 3;
        const int sg = t & 7;
        const float4* zr = (const float4*)(Z + (size_t)(row0 + r) * H);
        float s = 0.f;
        #pragma unroll
        for (int i = 0; i < 8; ++i) {
            float4 v = zr[sg * 8 + i];
            s += v.x * v.x + v.y * v.y + v.z * v.z + v.w * v.w;
        }
        s += __shfl_xor(s, 1);
        s += __shfl_xor(s, 2);
        s += __shfl_xor(s, 4);
        if (sg == 0) nzs[r] = s;
    }

    // ---- centroid k-quarter -> 64 VGPRs (lane = cluster) ----
    float4 c4[16];
    {
        const float4* cp = (const float4*)(C + (size_t)lane * H + wid * 64);
        #pragma unroll
        for (int i = 0; i < 16; ++i) c4[i] = cp[i];
    }
    {
        float s = 0.f;
        #pragma unroll
        for (int i = 0; i < 16; ++i)
            s += c4[i].x * c4[i].x + c4[i].y * c4[i].y + c4[i].z * c4[i].z + c4[i].w * c4[i].w;
        ncp[wid][lane] = s;
    }

    // ---- main: dot(z_r, c_lane) over this wave's k-quarter ----
    float acc[BM];
    #pragma unroll
    for (int r = 0; r < BM; ++r) acc[r] = 0.f;

    const float* Zb = Z + (size_t)row0 * H + wid * 64;  // wave-uniform base
    #pragma unroll
    for (int kb = 0; kb < 4; ++kb) {        // 4 chunks of 16 k
        #pragma unroll
        for (int r = 0; r < BM; ++r) {
            const float4* zp = (const float4*)(Zb + r * H + kb * 16);
            float4 z0 = zp[0], z1 = zp[1], z2 = zp[2], z3 = zp[3];
            float a = acc[r];
            a += z0.x * c4[kb*4+0].x + z0.y * c4[kb*4+0].y + z0.z * c4[kb*4+0].z + z0.w * c4[kb*4+0].w;
            a += z1.x * c4[kb*4+1].x + z1.y * c4[kb*4+1].y + z1.z * c4[kb*4+1].z + z1.w * c4[kb*4+1].w;
            a += z2.x * c4[kb*4+2].x + z2.y * c4[kb*4+2].y + z2.z * c4[kb*4+2].z + z2.w * c4[kb*4+2].w;
            a += z3.x * c4[kb*4+3].x + z3.y * c4[kb*4+3].y + z3.z * c4[kb*4+3].z + z3.w * c4[kb*4+3].w;
            acc[r] = a;
        }
    }

    #pragma unroll
    for (int r = 0; r < BM; ++r) pd[wid][r][lane] = acc[r];
    __syncthreads();

    // ---- combine k-quarters, Q, row-normalize, colsum partial ----
    const float ncT = ncp[0][lane] + ncp[1][lane] + ncp[2][lane] + ncp[3][lane];
    float colLocal = 0.f;
    #pragma unroll
    for (int j = 0; j < 8; ++j) {
        const int r = wid * 8 + j;
        float dot = pd[0][r][lane] + pd[1][r][lane] + pd[2][r][lane] + pd[3][r][lane];
        float d2  = fmaxf(nzs[r] + ncT - 2.f * dot, 0.f);
        float q   = 1.f / (1.f + sqrtf(d2));
        float s = q;
        s += __shfl_xor(s, 1);
        s += __shfl_xor(s, 2);
        s += __shfl_xor(s, 4);
        s += __shfl_xor(s, 8);
        s += __shfl_xor(s, 16);
        s += __shfl_xor(s, 32);
        float qn = q / s;
        out[(size_t)(row0 + r) * NC + lane] = qn;
        colLocal += qn;
    }
    csum[wid][lane] = colLocal;
    __syncthreads();
    if (wid == 0)
        ws[blockIdx.x * NC + lane] =
            csum[0][lane] + csum[1][lane] + csum[2][lane] + csum[3][lane];
}

// ---------------- K2: colsum reduce (redundant per block) + P ----------------
__global__ __launch_bounds__(256, 1) void k2_p(
    float* __restrict__ out, const float* __restrict__ ws)
{
    __shared__ float4 red[256];
    __shared__ float invcs[NC];
    const int t  = threadIdx.x;
    const int g  = t & 15;    // cluster-quad
    const int s0 = t >> 4;    // 0..15
    const float4* w4 = (const float4*)ws;   // [256 blocks][16 float4]
    float4 a = make_float4(0.f, 0.f, 0.f, 0.f);
    #pragma unroll
    for (int i = 0; i < 16; ++i) {
        float4 v = w4[(size_t)(s0 + 16 * i) * 16 + g];
        a.x += v.x; a.y += v.y; a.z += v.z; a.w += v.w;
    }
    red[t] = a;
    __syncthreads();
    if (t < 16) {
        float4 s = red[t];
        for (int i = 1; i < 16; ++i) {
            float4 v = red[i * 16 + t];
            s.x += v.x; s.y += v.y; s.z += v.z; s.w += v.w;
        }
        invcs[4 * t + 0] = 1.f / s.x;
        invcs[4 * t + 1] = 1.f / s.y;
        invcs[4 * t + 2] = 1.f / s.z;
        invcs[4 * t + 3] = 1.f / s.w;
    }
    __syncthreads();

    const int lane = t & 63;
    const int wid  = t >> 6;
    const float ic = invcs[lane];
    const int row0 = blockIdx.x * BM;
    #pragma unroll
    for (int j = 0; j < 8; ++j) {
        const int r = row0 + wid * 8 + j;
        float q  = out[(size_t)r * NC + lane];
        float pr = q * q * ic;
        float s = pr;
        s += __shfl_xor(s, 1);
        s += __shfl_xor(s, 2);
        s += __shfl_xor(s, 4);
        s += __shfl_xor(s, 8);
        s += __shfl_xor(s, 16);
        s += __shfl_xor(s, 32);
        out[(size_t)(M + r) * NC + lane] = pr / s;
    }
}

extern "C" void kernel_launch(void* const* d_in, const int* in_sizes, int n_in,
                              void* d_out, int out_size, void* d_ws, size_t ws_size,
                              hipStream_t stream) {
    const float* Z = (const float*)d_in[0];   // 8192 x 256
    const float* C = (const float*)d_in[1];   // 64 x 256
    float* out = (float*)d_out;               // [Q | P]
    float* ws  = (float*)d_ws;                // 256*64 colsum partials (64 KB)

    k1_fused<<<256, 256, 0, stream>>>(Z, C, out, ws);
    k2_p<<<256, 256, 0, stream>>>(out, ws);
}

// Round 3
// 75.702 us; speedup vs baseline: 1.1877x; 1.0760x over previous
//
#include <hip/hip_runtime.h>

// ClusterNet fused: Q = rownorm(1/(1+dist(z,C))), P = rownorm(Q^2/colsum(Q))
// z: 8192x256 fp32, C: 64x256 fp32. out = [Q (8192x64) | P (8192x64)] fp32.
// dist^2 = ||z||^2 + ||c||^2 - 2 z.c  (no cancellation risk: dist^2 ~ 512)

#define M  8192
#define NC 64
#define H  256
#define BM 16   // rows per block; grid = 512 -> 2 blocks/CU, 2 waves/SIMD

// ---------------- K1: distance + Q + per-block colsum partials ----------------
// grid 512 x 256 threads. lane = cluster; wave w handles k-quarter [64w, 64w+64).
// Centroid quarter lives in 64 VGPRs per lane; z is wave-uniform.
__global__ __launch_bounds__(256, 2) void k1_fused(
    const float* __restrict__ Z, const float* __restrict__ C,
    float* __restrict__ out, float* __restrict__ ws)
{
    __shared__ float pd[4][BM][NC];   // per-wave dot partials (16 KB)
    __shared__ float ncp[4][NC];      // per-wave ||c||^2 partials
    __shared__ float nzs[BM];         // row norms
    __shared__ float csum[4][NC];     // per-wave colsum partials

    const int t    = threadIdx.x;
    const int lane = t & 63;
    const int wid  = __builtin_amdgcn_readfirstlane(t >> 6);  // wave-uniform SGPR
    const int row0 = blockIdx.x * BM;

    // ---- row norms ||z_r||^2: 16 threads per row, shfl-reduce width 16 ----
    {
        const int r  = t >> 4;       // 0..15
        const int sg = t & 15;
        const float4* zr = (const float4*)(Z + (size_t)(row0 + r) * H);
        float s = 0.f;
        #pragma unroll
        for (int i = 0; i < 4; ++i) {
            float4 v = zr[sg * 4 + i];
            s += v.x * v.x + v.y * v.y + v.z * v.z + v.w * v.w;
        }
        s += __shfl_xor(s, 1);
        s += __shfl_xor(s, 2);
        s += __shfl_xor(s, 4);
        s += __shfl_xor(s, 8);
        if (sg == 0) nzs[r] = s;
    }

    // ---- centroid k-quarter -> 64 VGPRs (lane = cluster) ----
    float4 c4[16];
    {
        const float4* cp = (const float4*)(C + (size_t)lane * H + wid * 64);
        #pragma unroll
        for (int i = 0; i < 16; ++i) c4[i] = cp[i];
    }
    {
        float s = 0.f;
        #pragma unroll
        for (int i = 0; i < 16; ++i)
            s += c4[i].x * c4[i].x + c4[i].y * c4[i].y + c4[i].z * c4[i].z + c4[i].w * c4[i].w;
        ncp[wid][lane] = s;
    }

    // ---- main: dot(z_r, c_lane) over this wave's k-quarter ----
    float acc[BM];
    #pragma unroll
    for (int r = 0; r < BM; ++r) acc[r] = 0.f;

    const float* Zb = Z + (size_t)row0 * H + wid * 64;  // wave-uniform base
    #pragma unroll
    for (int kb = 0; kb < 4; ++kb) {        // 4 chunks of 16 k
        #pragma unroll
        for (int r = 0; r < BM; ++r) {
            const float4* zp = (const float4*)(Zb + r * H + kb * 16);
            float4 z0 = zp[0], z1 = zp[1], z2 = zp[2], z3 = zp[3];
            float a = acc[r];
            a += z0.x * c4[kb*4+0].x + z0.y * c4[kb*4+0].y + z0.z * c4[kb*4+0].z + z0.w * c4[kb*4+0].w;
            a += z1.x * c4[kb*4+1].x + z1.y * c4[kb*4+1].y + z1.z * c4[kb*4+1].z + z1.w * c4[kb*4+1].w;
            a += z2.x * c4[kb*4+2].x + z2.y * c4[kb*4+2].y + z2.z * c4[kb*4+2].z + z2.w * c4[kb*4+2].w;
            a += z3.x * c4[kb*4+3].x + z3.y * c4[kb*4+3].y + z3.z * c4[kb*4+3].z + z3.w * c4[kb*4+3].w;
            acc[r] = a;
        }
    }

    #pragma unroll
    for (int r = 0; r < BM; ++r) pd[wid][r][lane] = acc[r];
    __syncthreads();

    // ---- combine k-quarters, Q, row-normalize, colsum partial ----
    const float ncT = ncp[0][lane] + ncp[1][lane] + ncp[2][lane] + ncp[3][lane];
    float colLocal = 0.f;
    #pragma unroll
    for (int j = 0; j < 4; ++j) {
        const int r = wid * 4 + j;
        float dot = pd[0][r][lane] + pd[1][r][lane] + pd[2][r][lane] + pd[3][r][lane];
        float d2  = fmaxf(nzs[r] + ncT - 2.f * dot, 0.f);
        float q   = 1.f / (1.f + sqrtf(d2));
        float s = q;
        s += __shfl_xor(s, 1);
        s += __shfl_xor(s, 2);
        s += __shfl_xor(s, 4);
        s += __shfl_xor(s, 8);
        s += __shfl_xor(s, 16);
        s += __shfl_xor(s, 32);
        float qn = q / s;
        out[(size_t)(row0 + r) * NC + lane] = qn;
        colLocal += qn;
    }
    csum[wid][lane] = colLocal;
    __syncthreads();
    if (wid == 0)
        ws[blockIdx.x * NC + lane] =
            csum[0][lane] + csum[1][lane] + csum[2][lane] + csum[3][lane];
}

// ---------------- K2: colsum reduce (redundant per block) + P ----------------
__global__ __launch_bounds__(256, 2) void k2_p(
    float* __restrict__ out, const float* __restrict__ ws)
{
    __shared__ float4 red[256];
    __shared__ float invcs[NC];
    const int t  = threadIdx.x;
    const int g  = t & 15;    // cluster-quad
    const int s0 = t >> 4;    // 0..15
    const float4* w4 = (const float4*)ws;   // [512 blocks][16 float4]
    float4 a = make_float4(0.f, 0.f, 0.f, 0.f);
    #pragma unroll
    for (int i = 0; i < 32; ++i) {
        float4 v = w4[(size_t)(s0 + 16 * i) * 16 + g];
        a.x += v.x; a.y += v.y; a.z += v.z; a.w += v.w;
    }
    red[t] = a;
    __syncthreads();
    if (t < 16) {
        float4 s = red[t];
        for (int i = 1; i < 16; ++i) {
            float4 v = red[i * 16 + t];
            s.x += v.x; s.y += v.y; s.z += v.z; s.w += v.w;
        }
        invcs[4 * t + 0] = 1.f / s.x;
        invcs[4 * t + 1] = 1.f / s.y;
        invcs[4 * t + 2] = 1.f / s.z;
        invcs[4 * t + 3] = 1.f / s.w;
    }
    __syncthreads();

    const int lane = t & 63;
    const int wid  = t >> 6;
    const float ic = invcs[lane];
    const int row0 = blockIdx.x * BM;
    #pragma unroll
    for (int j = 0; j < 4; ++j) {
        const int r = row0 + wid * 4 + j;
        float q  = out[(size_t)r * NC + lane];
        float pr = q * q * ic;
        float s = pr;
        s += __shfl_xor(s, 1);
        s += __shfl_xor(s, 2);
        s += __shfl_xor(s, 4);
        s += __shfl_xor(s, 8);
        s += __shfl_xor(s, 16);
        s += __shfl_xor(s, 32);
        out[(size_t)(M + r) * NC + lane] = pr / s;
    }
}

extern "C" void kernel_launch(void* const* d_in, const int* in_sizes, int n_in,
                              void* d_out, int out_size, void* d_ws, size_t ws_size,
                              hipStream_t stream) {
    const float* Z = (const float*)d_in[0];   // 8192 x 256
    const float* C = (const float*)d_in[1];   // 64 x 256
    float* out = (float*)d_out;               // [Q | P]
    float* ws  = (float*)d_ws;                // 512*64 colsum partials (128 KB)

    k1_fused<<<512, 256, 0, stream>>>(Z, C, out, ws);
    k2_p<<<512, 256, 0, stream>>>(out, ws);
}

// Round 4
// 73.307 us; speedup vs baseline: 1.2265x; 1.0327x over previous
//
#include <hip/hip_runtime.h>

// ClusterNet fused: Q = rownorm(1/(1+dist(z,C))), P = rownorm(Q^2/colsum(Q))
// z: 8192x256 fp32, C: 64x256 fp32. out = [Q (8192x64) | P (8192x64)] fp32.
// dist^2 = ||z||^2 + ||c||^2 - 2 z.c  (no cancellation risk: dist^2 ~ 512)

#define M  8192
#define NC 64
#define H  256
#define BM 16   // rows per block; k1 grid = 512, 512 thr -> 2 blk/CU, 4 waves/SIMD

// ---------------- K1: distance + Q + per-block colsum partials ----------------
// grid 512 x 512 threads (8 waves). lane = cluster; wave w handles k-eighth
// [32w, 32w+32). Centroid eighth lives in 32 VGPRs per lane; z is wave-uniform.
__global__ __launch_bounds__(512, 4) void k1_fused(
    const float* __restrict__ Z, const float* __restrict__ C,
    float* __restrict__ out, float* __restrict__ ws)
{
    __shared__ float pd[8][BM][NC];   // per-wave dot partials (32 KB)
    __shared__ float ncp[8][NC];      // per-wave ||c||^2 partials
    __shared__ float nzs[BM];         // row norms
    __shared__ float csum[8][NC];     // per-wave colsum partials

    const int t    = threadIdx.x;
    const int lane = t & 63;
    const int wid  = __builtin_amdgcn_readfirstlane(t >> 6);  // wave-uniform SGPR
    const int row0 = blockIdx.x * BM;

    // ---- row norms ||z_r||^2: 32 threads per row, shfl-reduce width 32 ----
    {
        const int r  = t >> 5;       // 0..15
        const int sg = t & 31;
        const float4* zr = (const float4*)(Z + (size_t)(row0 + r) * H);
        float s = 0.f;
        #pragma unroll
        for (int i = 0; i < 2; ++i) {
            float4 v = zr[sg * 2 + i];
            s += v.x * v.x + v.y * v.y + v.z * v.z + v.w * v.w;
        }
        s += __shfl_xor(s, 1);
        s += __shfl_xor(s, 2);
        s += __shfl_xor(s, 4);
        s += __shfl_xor(s, 8);
        s += __shfl_xor(s, 16);
        if (sg == 0) nzs[r] = s;
    }

    // ---- centroid k-eighth -> 32 VGPRs (lane = cluster) ----
    float4 c4[8];
    {
        const float4* cp = (const float4*)(C + (size_t)lane * H + wid * 32);
        #pragma unroll
        for (int i = 0; i < 8; ++i) c4[i] = cp[i];
    }
    {
        float s = 0.f;
        #pragma unroll
        for (int i = 0; i < 8; ++i)
            s += c4[i].x * c4[i].x + c4[i].y * c4[i].y + c4[i].z * c4[i].z + c4[i].w * c4[i].w;
        ncp[wid][lane] = s;
    }

    // ---- main: dot(z_r, c_lane) over this wave's k-eighth ----
    float acc[BM];
    #pragma unroll
    for (int r = 0; r < BM; ++r) acc[r] = 0.f;

    const float* Zb = Z + (size_t)row0 * H + wid * 32;  // wave-uniform base
    #pragma unroll
    for (int kb = 0; kb < 2; ++kb) {        // 2 chunks of 16 k
        #pragma unroll
        for (int r = 0; r < BM; ++r) {
            const float4* zp = (const float4*)(Zb + r * H + kb * 16);
            float4 z0 = zp[0], z1 = zp[1], z2 = zp[2], z3 = zp[3];
            float a = acc[r];
            a += z0.x * c4[kb*4+0].x + z0.y * c4[kb*4+0].y + z0.z * c4[kb*4+0].z + z0.w * c4[kb*4+0].w;
            a += z1.x * c4[kb*4+1].x + z1.y * c4[kb*4+1].y + z1.z * c4[kb*4+1].z + z1.w * c4[kb*4+1].w;
            a += z2.x * c4[kb*4+2].x + z2.y * c4[kb*4+2].y + z2.z * c4[kb*4+2].z + z2.w * c4[kb*4+2].w;
            a += z3.x * c4[kb*4+3].x + z3.y * c4[kb*4+3].y + z3.z * c4[kb*4+3].z + z3.w * c4[kb*4+3].w;
            acc[r] = a;
        }
    }

    #pragma unroll
    for (int r = 0; r < BM; ++r) pd[wid][r][lane] = acc[r];
    __syncthreads();

    // ---- combine k-eighths, Q, row-normalize, colsum partial ----
    const float ncT = ncp[0][lane] + ncp[1][lane] + ncp[2][lane] + ncp[3][lane]
                    + ncp[4][lane] + ncp[5][lane] + ncp[6][lane] + ncp[7][lane];
    float colLocal = 0.f;
    #pragma unroll
    for (int j = 0; j < 2; ++j) {
        const int r = wid * 2 + j;
        float dot = pd[0][r][lane] + pd[1][r][lane] + pd[2][r][lane] + pd[3][r][lane]
                  + pd[4][r][lane] + pd[5][r][lane] + pd[6][r][lane] + pd[7][r][lane];
        float d2  = fmaxf(nzs[r] + ncT - 2.f * dot, 0.f);
        float q   = 1.f / (1.f + sqrtf(d2));
        float s = q;
        s += __shfl_xor(s, 1);
        s += __shfl_xor(s, 2);
        s += __shfl_xor(s, 4);
        s += __shfl_xor(s, 8);
        s += __shfl_xor(s, 16);
        s += __shfl_xor(s, 32);
        float qn = q / s;
        out[(size_t)(row0 + r) * NC + lane] = qn;
        colLocal += qn;
    }
    csum[wid][lane] = colLocal;
    __syncthreads();
    if (wid == 0)
        ws[blockIdx.x * NC + lane] =
            csum[0][lane] + csum[1][lane] + csum[2][lane] + csum[3][lane] +
            csum[4][lane] + csum[5][lane] + csum[6][lane] + csum[7][lane];
}

// ---------------- K2: colsum reduce (redundant per block) + P ----------------
__global__ __launch_bounds__(256, 2) void k2_p(
    float* __restrict__ out, const float* __restrict__ ws)
{
    __shared__ float4 red[256];
    __shared__ float invcs[NC];
    const int t  = threadIdx.x;
    const int g  = t & 15;    // cluster-quad
    const int s0 = t >> 4;    // 0..15
    const float4* w4 = (const float4*)ws;   // [512 blocks][16 float4]
    float4 a = make_float4(0.f, 0.f, 0.f, 0.f);
    #pragma unroll
    for (int i = 0; i < 32; ++i) {
        float4 v = w4[(size_t)(s0 + 16 * i) * 16 + g];
        a.x += v.x; a.y += v.y; a.z += v.z; a.w += v.w;
    }
    red[t] = a;
    __syncthreads();
    if (t < 16) {
        float4 s = red[t];
        for (int i = 1; i < 16; ++i) {
            float4 v = red[i * 16 + t];
            s.x += v.x; s.y += v.y; s.z += v.z; s.w += v.w;
        }
        invcs[4 * t + 0] = 1.f / s.x;
        invcs[4 * t + 1] = 1.f / s.y;
        invcs[4 * t + 2] = 1.f / s.z;
        invcs[4 * t + 3] = 1.f / s.w;
    }
    __syncthreads();

    const int lane = t & 63;
    const int wid  = t >> 6;
    const float ic = invcs[lane];
    const int row0 = blockIdx.x * BM;
    #pragma unroll
    for (int j = 0; j < 4; ++j) {
        const int r = row0 + wid * 4 + j;
        float q  = out[(size_t)r * NC + lane];
        float pr = q * q * ic;
        float s = pr;
        s += __shfl_xor(s, 1);
        s += __shfl_xor(s, 2);
        s += __shfl_xor(s, 4);
        s += __shfl_xor(s, 8);
        s += __shfl_xor(s, 16);
        s += __shfl_xor(s, 32);
        out[(size_t)(M + r) * NC + lane] = pr / s;
    }
}

extern "C" void kernel_launch(void* const* d_in, const int* in_sizes, int n_in,
                              void* d_out, int out_size, void* d_ws, size_t ws_size,
                              hipStream_t stream) {
    const float* Z = (const float*)d_in[0];   // 8192 x 256
    const float* C = (const float*)d_in[1];   // 64 x 256
    float* out = (float*)d_out;               // [Q | P]
    float* ws  = (float*)d_ws;                // 512*64 colsum partials (128 KB)

    k1_fused<<<512, 512, 0, stream>>>(Z, C, out, ws);
    k2_p<<<512, 256, 0, stream>>>(out, ws);
}